// Round 1
// baseline (3130.521 us; speedup 1.0000x reference)
//
#include <hip/hip_runtime.h>
#include <hip/hip_fp16.h>

// Problem constants
#define Bb 128
#define Tt 512
#define Ee 300
#define Hh 150
#define GP 640   // gates padded 600 -> 640 (one gate per thread, balanced waves)
#define K4N 38   // ceil(150/4) k-groups for W_hh (padded to 152)

// Workspace byte offsets
#define WTIH_OFF   0ul
#define WTIH_BYTES (2ul*300*640*4)              // 1,536,000
#define WHH4_OFF   (WTIH_OFF + WTIH_BYTES)
#define WHH4_BYTES (2ul*K4N*640*4*4)            // 778,240
#define BIAS_OFF   (WHH4_OFF + WHH4_BYTES)      // 2,314,240
#define BIAS_BYTES (2ul*640*4)
#define XG_OFF     (4ul*1024*1024)              // fp16 xg: 2*128*512*640*2 = 167.8 MB

__device__ __forceinline__ float tanh_fast(float v) {
    float av = fminf(fabsf(v), 15.f);
    float e  = __expf(2.f * av);
    float r  = (e - 1.f) / (e + 1.f);
    return copysignf(r, v);
}
__device__ __forceinline__ float sigmoid_fast(float v) {
    return 1.f / (1.f + __expf(-v));
}

// ---------------- Kernel 0: pack weights (k-major, padded) ----------------
__global__ void pack_weights(const float* __restrict__ Wih_f, const float* __restrict__ Whh_f,
                             const float* __restrict__ b_f,
                             const float* __restrict__ Wih_b, const float* __restrict__ Whh_b,
                             const float* __restrict__ b_b,
                             float* __restrict__ Wt_ih, float* __restrict__ Whh4,
                             float* __restrict__ bias_p) {
    int idx = blockIdx.x * 256 + threadIdx.x;
    const int T1 = 2 * 300 * 640;
    const int T2 = 2 * K4N * 640 * 4;
    const int T3 = 2 * 640;
    if (idx < T1) {
        // Wt_ih[dir][e][j] = W_ih[j][e]
        int dir = idx / (300 * 640);
        int rem = idx % (300 * 640);
        int e = rem / 640, j = rem % 640;
        const float* W = dir ? Wih_b : Wih_f;
        Wt_ih[idx] = (j < 600) ? W[j * 300 + e] : 0.f;
    } else if ((idx -= T1) < T2) {
        // Whh4[dir][k4][j][c] = W_hh[j][k4*4+c]
        int dir = idx / (K4N * 640 * 4);
        int rem = idx % (K4N * 640 * 4);
        int k4 = rem / (640 * 4);
        int r2 = rem % (640 * 4);
        int j = r2 / 4, c = r2 % 4;
        int k = k4 * 4 + c;
        const float* W = dir ? Whh_b : Whh_f;
        Whh4[dir * (K4N * 640 * 4) + (k4 * 640 + j) * 4 + c] =
            (j < 600 && k < 150) ? W[j * 150 + k] : 0.f;
    } else if ((idx -= T2) < T3) {
        int dir = idx / 640, j = idx % 640;
        const float* bb = dir ? b_b : b_f;
        bias_p[idx] = (j < 600) ? bb[j] : 0.f;
    }
}

// ---------------- Kernel 1: xg GEMM (fp32 compute, fp16 store) ----------------
// xg[dir][b][step][j] = sum_e x[b][t(step,dir)][e] * W_ih_dir[j][e] + b_dir[j]
// M' = 2*128*512 = 131072 rows, N = 640 (padded), K = 300. 64x128 tile, BK=12.
__global__ __launch_bounds__(256) void gemm_xg(const float* __restrict__ x,
                                               const float* __restrict__ Wt_ih,
                                               const float* __restrict__ bias_p,
                                               __half* __restrict__ xg) {
    __shared__ float As[12][64];
    __shared__ float Bs[12][128];
    const int tid  = threadIdx.x;
    const int row0 = blockIdx.x * 64;
    const int col0 = blockIdx.y * 128;
    const int dir  = row0 >> 16;      // constant within block (65536 % 64 == 0)

    // A staging assignment: 4 threads per row, 3 consecutive k each
    const int mm = tid >> 2, q = tid & 3;
    int base_a;
    {
        int r  = row0 + mm;
        int b  = (r >> 9) & 127, st = r & 511;
        int tx_ = dir ? (511 - st) : st;
        base_a = (b * 512 + tx_) * 300;
    }
    const int ty = tid >> 4, tx = tid & 15;
    const int tm = ty * 4, tn = tx * 8;
    float acc[4][8];
#pragma unroll
    for (int i = 0; i < 4; ++i)
#pragma unroll
        for (int j = 0; j < 8; ++j) acc[i][j] = 0.f;

    const float* Bsrc = Wt_ih + dir * 300 * 640 + col0;

    for (int it = 0; it < 25; ++it) {
        int k0 = it * 12;
#pragma unroll
        for (int c = 0; c < 3; ++c) {
            int kk = q * 3 + c;
            As[kk][mm] = x[base_a + k0 + kk];
        }
#pragma unroll
        for (int c = 0; c < 3; ++c) {
            int i2 = tid * 3 + c;          // 0..767 float2 units
            int kk = i2 >> 6, n2 = i2 & 63;
            *(float2*)&Bs[kk][n2 * 2] = *(const float2*)&Bsrc[(k0 + kk) * 640 + n2 * 2];
        }
        __syncthreads();
#pragma unroll
        for (int kk = 0; kk < 12; ++kk) {
            float4 a  = *(const float4*)&As[kk][tm];
            float4 b0 = *(const float4*)&Bs[kk][tn];
            float4 b1 = *(const float4*)&Bs[kk][tn + 4];
            float av[4] = {a.x, a.y, a.z, a.w};
            float bv[8] = {b0.x, b0.y, b0.z, b0.w, b1.x, b1.y, b1.z, b1.w};
#pragma unroll
            for (int mi = 0; mi < 4; ++mi)
#pragma unroll
                for (int ni = 0; ni < 8; ++ni) acc[mi][ni] += av[mi] * bv[ni];
        }
        __syncthreads();
    }

    float bias[8];
#pragma unroll
    for (int n = 0; n < 8; ++n) bias[n] = bias_p[dir * 640 + col0 + tn + n];
#pragma unroll
    for (int mi = 0; mi < 4; ++mi) {
        int r = row0 + tm + mi;
        union { __half h[8]; uint4 u; } pk;
#pragma unroll
        for (int n = 0; n < 8; ++n) pk.h[n] = __float2half(acc[mi][n] + bias[n]);
        *reinterpret_cast<uint4*>(xg + (size_t)r * 640 + col0 + tn) = pk.u;
    }
}

// ---------------- Kernel 2: recurrence + pooling ----------------
// One block per (direction, 4-sample group): 64 blocks x 640 threads.
// Thread j computes gate column j for 4 samples; threads < 600 also own one
// (sample, hidden-unit) for the c/h update and pooling.
__global__ __launch_bounds__(640) void lstm_rec(const float4* __restrict__ Whh4,
                                                const __half* __restrict__ xg,
                                                const int* __restrict__ lens,
                                                float* __restrict__ out) {
    __shared__ float h4[152][4];   // h[k][sample], rows 150/151 stay zero
    __shared__ float gl[GP][4];    // gate[j][sample]
    const int tid = threadIdx.x;
    const int dir = blockIdx.x & 1;
    const int s0  = (blockIdx.x >> 1) * 4;

    for (int i = tid; i < 152 * 4; i += 640) ((float*)h4)[i] = 0.f;

    float c_s = 0.f, hsum = 0.f, hlast = 0.f;
    int uu = 0, ss = 0, markLast = -1, Lv = 1;
    if (tid < 600) {
        ss = tid / 150;
        uu = tid - ss * 150;
        Lv = lens[s0 + ss];
        markLast = dir ? (Tt - Lv) : (Lv - 1);  // bwd: step T-L == real t L-1
    }
    const float4* wbase = Whh4 + dir * (K4N * 640) + tid;
    const __half* xbase = xg + (size_t)(dir * 128 + s0) * 512 * 640 + tid;
    __syncthreads();

    for (int step = 0; step < Tt; ++step) {
        const __half* xp = xbase + (size_t)step * 640;
        float a0 = __half2float(xp[0]);
        float a1 = __half2float(xp[512 * 640]);
        float a2 = __half2float(xp[2 * 512 * 640]);
        float a3 = __half2float(xp[3 * 512 * 640]);
#pragma unroll 2
        for (int k4 = 0; k4 < K4N; ++k4) {
            float4 w  = wbase[k4 * 640];
            float4 h0 = *(const float4*)&h4[k4 * 4 + 0][0];
            float4 h1 = *(const float4*)&h4[k4 * 4 + 1][0];
            float4 h2 = *(const float4*)&h4[k4 * 4 + 2][0];
            float4 h3 = *(const float4*)&h4[k4 * 4 + 3][0];
            a0 += w.x * h0.x + w.y * h1.x + w.z * h2.x + w.w * h3.x;
            a1 += w.x * h0.y + w.y * h1.y + w.z * h2.y + w.w * h3.y;
            a2 += w.x * h0.z + w.y * h1.z + w.z * h2.z + w.w * h3.z;
            a3 += w.x * h0.w + w.y * h1.w + w.z * h2.w + w.w * h3.w;
        }
        *(float4*)&gl[tid][0] = make_float4(a0, a1, a2, a3);
        __syncthreads();
        if (tid < 600) {
            float xi = gl[uu][ss];
            float xf = gl[150 + uu][ss];
            float xc = gl[300 + uu][ss];
            float xo = gl[450 + uu][ss];
            float i_ = sigmoid_fast(xi);
            float f_ = sigmoid_fast(xf);
            float g_ = tanh_fast(xc);
            float o_ = sigmoid_fast(xo);
            c_s = f_ * c_s + i_ * g_;
            float h = o_ * tanh_fast(c_s);
            bool in = dir ? (step >= markLast) : (step < Lv);
            if (in) hsum += h;
            if (step == markLast) hlast = h;
            h4[uu][ss] = h;
        }
        __syncthreads();
    }

    if (tid < 600) {
        int b = s0 + ss;
        out[b * 600 + dir * 150 + uu]       = tanh_fast(hsum / (float)Lv);
        out[b * 600 + 300 + dir * 150 + uu] = tanh_fast(hlast);
    }
}

// ---------------- launch ----------------
extern "C" void kernel_launch(void* const* d_in, const int* in_sizes, int n_in,
                              void* d_out, int out_size, void* d_ws, size_t ws_size,
                              hipStream_t stream) {
    const float* x     = (const float*)d_in[0];
    const int*   lens  = (const int*)d_in[1];
    const float* Wih_f = (const float*)d_in[2];
    const float* Whh_f = (const float*)d_in[3];
    const float* b_f   = (const float*)d_in[4];
    const float* Wih_b = (const float*)d_in[5];
    const float* Whh_b = (const float*)d_in[6];
    const float* b_b   = (const float*)d_in[7];
    float* out = (float*)d_out;
    char*  ws  = (char*)d_ws;

    float*  Wt_ih  = (float*)(ws + WTIH_OFF);
    float*  Whh4   = (float*)(ws + WHH4_OFF);
    float*  bias_p = (float*)(ws + BIAS_OFF);
    __half* xg     = (__half*)(ws + XG_OFF);

    {
        int total = 2 * 300 * 640 + 2 * K4N * 640 * 4 + 2 * 640;
        int blocks = (total + 255) / 256;
        pack_weights<<<blocks, 256, 0, stream>>>(Wih_f, Whh_f, b_f, Wih_b, Whh_b, b_b,
                                                 Wt_ih, Whh4, bias_p);
    }
    {
        dim3 grid(2048, 5);  // 131072/64 rows, 640/128 cols
        gemm_xg<<<grid, 256, 0, stream>>>(x, Wt_ih, bias_p, xg);
    }
    {
        lstm_rec<<<64, 640, 0, stream>>>((const float4*)Whh4, xg, lens, out);
    }
}

// Round 2
// 1142.793 us; speedup vs baseline: 2.7394x; 2.7394x over previous
//
#include <hip/hip_runtime.h>
#include <hip/hip_fp16.h>

// Problem constants
#define Bb 128
#define Tt 512
#define Ee 300
#define Hh 150
#define GP 640   // gates padded 600 -> 640

// Workspace byte offsets
#define WTIH_OFF   0ul
#define WTIH_BYTES (2ul*300*640*4)              // 1,536,000
#define WHH2_OFF   (WTIH_OFF + WTIH_BYTES)
#define WHH2_BYTES (2ul*20*640*4*4)             // 409,600 (uint-packed half2)
#define BIAS_OFF   (WHH2_OFF + WHH2_BYTES)
#define BIAS_BYTES (2ul*640*4)
#define XG_OFF     (4ul*1024*1024)              // fp16 xg: 2*128*512*640*2 = 167.8 MB

typedef _Float16 h2vec __attribute__((ext_vector_type(2)));

__device__ __forceinline__ float fdot2(unsigned a, unsigned b, float c) {
#if __has_builtin(__builtin_amdgcn_fdot2)
    return __builtin_amdgcn_fdot2(__builtin_bit_cast(h2vec, a),
                                  __builtin_bit_cast(h2vec, b), c, false);
#else
    __half2 ha = __builtin_bit_cast(__half2, a);
    __half2 hb = __builtin_bit_cast(__half2, b);
    return c + __half2float(ha.x) * __half2float(hb.x)
             + __half2float(ha.y) * __half2float(hb.y);
#endif
}

__device__ __forceinline__ float tanh_fast(float v) {
    float av = fminf(fabsf(v), 15.f);
    float e  = __expf(2.f * av);
    float r  = (e - 1.f) / (e + 1.f);
    return copysignf(r, v);
}
__device__ __forceinline__ float sigmoid_fast(float v) {
    return 1.f / (1.f + __expf(-v));
}

// ---------------- Kernel 0: pack weights ----------------
// Wt_ih[dir][e][j] = W_ih[j][e]  (fp32, for the xg GEMM)
// Whh2[((dir*20 + r)*640 + j)*4 + c] = half2(W_hh[j][8r+2c], W_hh[j][8r+2c+1])
__global__ void pack_weights(const float* __restrict__ Wih_f, const float* __restrict__ Whh_f,
                             const float* __restrict__ b_f,
                             const float* __restrict__ Wih_b, const float* __restrict__ Whh_b,
                             const float* __restrict__ b_b,
                             float* __restrict__ Wt_ih, unsigned* __restrict__ Whh2,
                             float* __restrict__ bias_p) {
    int idx = blockIdx.x * 256 + threadIdx.x;
    const int T1 = 2 * 300 * 640;     // 384000
    const int T2 = 2 * 20 * 640 * 4;  // 102400
    const int T3 = 2 * 640;
    if (idx < T1) {
        int dir = idx / (300 * 640);
        int rem = idx % (300 * 640);
        int e = rem / 640, j = rem % 640;
        const float* W = dir ? Wih_b : Wih_f;
        Wt_ih[idx] = (j < 600) ? W[j * 300 + e] : 0.f;
    } else if ((idx -= T1) < T2) {
        int dir  = idx / 51200;
        int rem  = idx % 51200;
        int r    = rem / 2560;
        int rem2 = rem % 2560;
        int j = rem2 >> 2, c = rem2 & 3;
        int k = r * 8 + c * 2;
        const float* W = dir ? Whh_b : Whh_f;
        float lo = (j < 600 && k     < 150) ? W[j * 150 + k]     : 0.f;
        float hi = (j < 600 && k + 1 < 150) ? W[j * 150 + k + 1] : 0.f;
        union { __half h[2]; unsigned u; } pk;
        pk.h[0] = __float2half(lo);
        pk.h[1] = __float2half(hi);
        Whh2[idx] = pk.u;
    } else if ((idx -= T2) < T3) {
        int dir = idx / 640, j = idx % 640;
        const float* bb = dir ? b_b : b_f;
        bias_p[idx] = (j < 600) ? bb[j] : 0.f;
    }
}

// ---------------- Kernel 1: xg GEMM (fp32 compute, fp16 store) ----------------
__global__ __launch_bounds__(256) void gemm_xg(const float* __restrict__ x,
                                               const float* __restrict__ Wt_ih,
                                               const float* __restrict__ bias_p,
                                               __half* __restrict__ xg) {
    __shared__ float As[12][64];
    __shared__ float Bs[12][128];
    const int tid  = threadIdx.x;
    const int row0 = blockIdx.x * 64;
    const int col0 = blockIdx.y * 128;
    const int dir  = row0 >> 16;

    const int mm = tid >> 2, q = tid & 3;
    int base_a;
    {
        int r  = row0 + mm;
        int b  = (r >> 9) & 127, st = r & 511;
        int tx_ = dir ? (511 - st) : st;
        base_a = (b * 512 + tx_) * 300;
    }
    const int ty = tid >> 4, tx = tid & 15;
    const int tm = ty * 4, tn = tx * 8;
    float acc[4][8];
#pragma unroll
    for (int i = 0; i < 4; ++i)
#pragma unroll
        for (int j = 0; j < 8; ++j) acc[i][j] = 0.f;

    const float* Bsrc = Wt_ih + dir * 300 * 640 + col0;

    for (int it = 0; it < 25; ++it) {
        int k0 = it * 12;
#pragma unroll
        for (int c = 0; c < 3; ++c) {
            int kk = q * 3 + c;
            As[kk][mm] = x[base_a + k0 + kk];
        }
#pragma unroll
        for (int c = 0; c < 3; ++c) {
            int i2 = tid * 3 + c;
            int kk = i2 >> 6, n2 = i2 & 63;
            *(float2*)&Bs[kk][n2 * 2] = *(const float2*)&Bsrc[(k0 + kk) * 640 + n2 * 2];
        }
        __syncthreads();
#pragma unroll
        for (int kk = 0; kk < 12; ++kk) {
            float4 a  = *(const float4*)&As[kk][tm];
            float4 b0 = *(const float4*)&Bs[kk][tn];
            float4 b1 = *(const float4*)&Bs[kk][tn + 4];
            float av[4] = {a.x, a.y, a.z, a.w};
            float bv[8] = {b0.x, b0.y, b0.z, b0.w, b1.x, b1.y, b1.z, b1.w};
#pragma unroll
            for (int mi = 0; mi < 4; ++mi)
#pragma unroll
                for (int ni = 0; ni < 8; ++ni) acc[mi][ni] += av[mi] * bv[ni];
        }
        __syncthreads();
    }

    float bias[8];
#pragma unroll
    for (int n = 0; n < 8; ++n) bias[n] = bias_p[dir * 640 + col0 + tn + n];
#pragma unroll
    for (int mi = 0; mi < 4; ++mi) {
        int r = row0 + tm + mi;
        union { __half h[8]; uint4 u; } pk;
#pragma unroll
        for (int n = 0; n < 8; ++n) pk.h[n] = __float2half(acc[mi][n] + bias[n]);
        *reinterpret_cast<uint4*>(xg + (size_t)r * 640 + col0 + tn) = pk.u;
    }
}

// ---------------- Kernel 2: recurrence + pooling ----------------
// One block per chain (dir, sample): 256 blocks x 640 threads (10 waves).
// Thread j owns gate column j; its 150 W_hh weights live in 20 uint4 VGPRs
// as packed fp16 pairs. h lives in LDS as fp16 (160 halfs, broadcast reads).
__global__ __launch_bounds__(640, 1) void lstm_rec(const uint4* __restrict__ Whh2,
                                                   const __half* __restrict__ xg,
                                                   const int* __restrict__ lens,
                                                   float* __restrict__ out) {
    __shared__ unsigned h2[80];    // 160 packed fp16 h values (150 used, rest 0)
    __shared__ float gl[GP];       // gate exchange, stride-4B conflict-free
    const int tid = threadIdx.x;
    const int dir = blockIdx.x & 1;
    const int b   = blockIdx.x >> 1;

    // preload this thread's gate column of W_hh (coalesced, one-time)
    uint4 w[20];
    const uint4* wsrc = Whh2 + dir * (20 * 640) + tid;
#pragma unroll
    for (int r = 0; r < 20; ++r) w[r] = wsrc[r * 640];

    if (tid < 80) h2[tid] = 0u;

    float c_s = 0.f, hsum = 0.f, hlast = 0.f;
    int Lv = 1, markLast = -1;
    if (tid < 150) {
        Lv = lens[b];
        markLast = dir ? (Tt - Lv) : (Lv - 1);
    }

    const __half* xbase = xg + (size_t)(dir * 128 + b) * 512 * 640 + tid;
    __syncthreads();

    float xv = __half2float(xbase[0]);
    const uint4* h4 = (const uint4*)h2;
    for (int step = 0; step < Tt; ++step) {
        int sp = (step + 1 < Tt) ? step + 1 : (Tt - 1);
        __half xn = xbase[(size_t)sp * 640];   // prefetch next step's xg

        float a0 = xv, a1 = 0.f, a2 = 0.f, a3 = 0.f;
#pragma unroll
        for (int r = 0; r < 20; ++r) {
            uint4 hv = h4[r];                   // LDS broadcast
            a0 = fdot2(hv.x, w[r].x, a0);
            a1 = fdot2(hv.y, w[r].y, a1);
            a2 = fdot2(hv.z, w[r].z, a2);
            a3 = fdot2(hv.w, w[r].w, a3);
        }
        gl[tid] = (a0 + a1) + (a2 + a3);
        __syncthreads();

        if (tid < 150) {
            float i_ = sigmoid_fast(gl[tid]);
            float f_ = sigmoid_fast(gl[150 + tid]);
            float g_ = tanh_fast(gl[300 + tid]);
            float o_ = sigmoid_fast(gl[450 + tid]);
            c_s = f_ * c_s + i_ * g_;
            float h = o_ * tanh_fast(c_s);
            bool in = dir ? (step >= markLast) : (step < Lv);
            if (in) hsum += h;
            if (step == markLast) hlast = h;
            ((__half*)h2)[tid] = __float2half(h);
        }
        __syncthreads();
        xv = __half2float(xn);
    }

    if (tid < 150) {
        out[b * 600 + dir * 150 + tid]       = tanh_fast(hsum / (float)Lv);
        out[b * 600 + 300 + dir * 150 + tid] = tanh_fast(hlast);
    }
}

// ---------------- launch ----------------
extern "C" void kernel_launch(void* const* d_in, const int* in_sizes, int n_in,
                              void* d_out, int out_size, void* d_ws, size_t ws_size,
                              hipStream_t stream) {
    const float* x     = (const float*)d_in[0];
    const int*   lens  = (const int*)d_in[1];
    const float* Wih_f = (const float*)d_in[2];
    const float* Whh_f = (const float*)d_in[3];
    const float* b_f   = (const float*)d_in[4];
    const float* Wih_b = (const float*)d_in[5];
    const float* Whh_b = (const float*)d_in[6];
    const float* b_b   = (const float*)d_in[7];
    float* out = (float*)d_out;
    char*  ws  = (char*)d_ws;

    float*    Wt_ih  = (float*)(ws + WTIH_OFF);
    unsigned* Whh2   = (unsigned*)(ws + WHH2_OFF);
    float*    bias_p = (float*)(ws + BIAS_OFF);
    __half*   xg     = (__half*)(ws + XG_OFF);

    {
        int total = 2 * 300 * 640 + 2 * 20 * 640 * 4 + 2 * 640;
        int blocks = (total + 255) / 256;
        pack_weights<<<blocks, 256, 0, stream>>>(Wih_f, Whh_f, b_f, Wih_b, Whh_b, b_b,
                                                 Wt_ih, Whh2, bias_p);
    }
    {
        dim3 grid(2048, 5);
        gemm_xg<<<grid, 256, 0, stream>>>(x, Wt_ih, bias_p, xg);
    }
    {
        lstm_rec<<<256, 640, 0, stream>>>((const uint4*)Whh2, xg, lens, out);
    }
}

// Round 3
// 703.546 us; speedup vs baseline: 4.4496x; 1.6243x over previous
//
#include <hip/hip_runtime.h>
#include <hip/hip_fp16.h>

#define Tt 512
#define GP 640

typedef _Float16 f16x8 __attribute__((ext_vector_type(8)));
typedef float    f32x4 __attribute__((ext_vector_type(4)));
typedef _Float16 h2vec __attribute__((ext_vector_type(2)));

// Workspace byte offsets
#define BP16_OFF 0ul                              // fp16 B panel [1280][320]
#define BP16_BYTES (2ul*1280*320)                 // 819,200
#define WHH2_OFF (BP16_OFF + BP16_BYTES)
#define WHH2_BYTES (4ul*2*20*640*4)               // 409,600
#define BIAS_OFF (WHH2_OFF + WHH2_BYTES)
#define BIAS_BYTES (4ul*1280)
#define XG_OFF   (4ul*1024*1024)                  // fp16 xg [65536][1280] = 167.8 MB

__device__ __forceinline__ float fdot2(unsigned a, unsigned b, float c) {
#if __has_builtin(__builtin_amdgcn_fdot2)
    return __builtin_amdgcn_fdot2(__builtin_bit_cast(h2vec, a),
                                  __builtin_bit_cast(h2vec, b), c, false);
#else
    __half2 ha = __builtin_bit_cast(__half2, a);
    __half2 hb = __builtin_bit_cast(__half2, b);
    return c + __half2float(ha.x) * __half2float(hb.x)
             + __half2float(ha.y) * __half2float(hb.y);
#endif
}

__device__ __forceinline__ float tanh_fast(float v) {
    float av = fminf(fabsf(v), 15.f);
    float e  = __expf(2.f * av);
    float r  = (e - 1.f) / (e + 1.f);
    return copysignf(r, v);
}
__device__ __forceinline__ float sigmoid_fast(float v) {
    return 1.f / (1.f + __expf(-v));
}

// ---------------- Kernel 0: pack weights ----------------
// Bp[n][k] fp16: n = dir*640+j (1280, j-pad 600..639 = 0), k = e (320, pad 300..319 = 0)
// Whh2 packed half2 (unchanged), bias_p fp32 [1280]
__global__ void pack_weights(const float* __restrict__ Wih_f, const float* __restrict__ Whh_f,
                             const float* __restrict__ b_f,
                             const float* __restrict__ Wih_b, const float* __restrict__ Whh_b,
                             const float* __restrict__ b_b,
                             __half* __restrict__ Bp, unsigned* __restrict__ Whh2,
                             float* __restrict__ bias_p) {
    int idx = blockIdx.x * 256 + threadIdx.x;
    const int T1 = 1280 * 320;
    const int T2 = 2 * 20 * 640 * 4;
    const int T3 = 1280;
    if (idx < T1) {
        int n = idx / 320, k = idx % 320;
        int dir = (n >= 640), j = n - dir * 640;
        const float* W = dir ? Wih_b : Wih_f;
        Bp[idx] = __float2half((j < 600 && k < 300) ? W[j * 300 + k] : 0.f);
    } else if ((idx -= T1) < T2) {
        int dir  = idx / 51200;
        int rem  = idx % 51200;
        int r    = rem / 2560;
        int rem2 = rem % 2560;
        int j = rem2 >> 2, c = rem2 & 3;
        int k = r * 8 + c * 2;
        const float* W = dir ? Whh_b : Whh_f;
        float lo = (j < 600 && k     < 150) ? W[j * 150 + k]     : 0.f;
        float hi = (j < 600 && k + 1 < 150) ? W[j * 150 + k + 1] : 0.f;
        union { __half h[2]; unsigned u; } pk;
        pk.h[0] = __float2half(lo);
        pk.h[1] = __float2half(hi);
        Whh2[idx] = pk.u;
    } else if ((idx -= T2) < T3) {
        int n = idx;
        int dir = (n >= 640), j = n - dir * 640;
        const float* bb = dir ? b_b : b_f;
        bias_p[n] = (j < 600) ? bb[j] : 0.f;
    }
}

// ---------------- Kernel 1: xg GEMM via MFMA ----------------
// C[m][n] = sum_k A[m][k] B^T[n][k],  A = x fp32->fp16, B^T = Bp.
// BM=128, BN=128, 4 waves. Full-K B panel in LDS (80 KB, XOR-swizzled),
// A fragments streamed global->reg double-buffered. No K-loop barriers.
__global__ __launch_bounds__(256) void gemm_xg(const float* __restrict__ x,
                                               const uint4* __restrict__ Bp,
                                               const float* __restrict__ bias_p,
                                               __half* __restrict__ xg) {
    __shared__ uint4 Bsh[5120];   // [128 n][40 chunks of 8 halfs], chunk ^= (n&7)
    const int tid = threadIdx.x;
    const int bid = blockIdx.x;
    // XCD-chunked mapping: the 10 nb-blocks of one mb share an XCD L2
    const int xcd = bid & 7, li = bid >> 3;       // 5120 = 8 * 640
    const int mb  = xcd * 64 + li / 10;
    const int nb  = li % 10;

    {   // stage B panel (one-time)
        const uint4* src = Bp + (size_t)nb * 128 * 40;
        for (int c = tid; c < 5120; c += 256) {
            int n = c / 40, ch = c - n * 40;
            Bsh[n * 40 + (ch ^ (n & 7))] = src[c];
        }
    }

    const int w  = tid >> 6;
    const int l  = tid & 63;
    const int wr = w >> 1, wc = w & 1;
    const int lr = l & 15, kg = l >> 4;

    f32x4 acc[4][4];
#pragma unroll
    for (int mf = 0; mf < 4; ++mf)
#pragma unroll
        for (int nf = 0; nf < 4; ++nf) acc[mf][nf] = (f32x4)0.f;

    const float* arow0 = x + (size_t)(mb * 128 + wr * 64 + lr) * 300 + kg * 8;
    const float* arow1 = arow0 + 16 * 300;
    const float* arow2 = arow0 + 32 * 300;
    const float* arow3 = arow0 + 48 * 300;
    const float4 fz4 = make_float4(0.f, 0.f, 0.f, 0.f);

    float cur[2][4][8];
#define LOADA(BUF, KB, GUARD)                                                   \
    {                                                                           \
        const float* ap_[4] = {arow0, arow1, arow2, arow3};                     \
        _Pragma("unroll")                                                       \
        for (int mf = 0; mf < 4; ++mf) {                                        \
            const float* ap = ap_[mf] + (KB) * 32;                              \
            *(float4*)&cur[BUF][mf][0] =                                        \
                (!(GUARD) || (KB) * 32 + kg * 8 < 300) ? *(const float4*)ap : fz4; \
            *(float4*)&cur[BUF][mf][4] =                                        \
                (!(GUARD) || (KB) * 32 + kg * 8 + 4 < 300) ? *(const float4*)(ap + 4) : fz4; \
        }                                                                       \
    }

    __syncthreads();   // B panel ready

    LOADA(0, 0, false);
#pragma unroll
    for (int kb = 0; kb < 10; ++kb) {
        const int pb = kb & 1, nx = pb ^ 1;
        if (kb < 8)       { LOADA(nx, kb + 1, false); }
        else if (kb == 8) { LOADA(nx, 9, true); }

        uint4 bf[4];
#pragma unroll
        for (int nf = 0; nf < 4; ++nf)
            bf[nf] = Bsh[(wc * 64 + nf * 16 + lr) * 40 + ((kb * 4 + kg) ^ (lr & 7))];

        f16x8 af[4];
#pragma unroll
        for (int mf = 0; mf < 4; ++mf)
#pragma unroll
            for (int i = 0; i < 8; ++i) af[mf][i] = (_Float16)cur[pb][mf][i];

#pragma unroll
        for (int mf = 0; mf < 4; ++mf)
#pragma unroll
            for (int nf = 0; nf < 4; ++nf)
                acc[mf][nf] = __builtin_amdgcn_mfma_f32_16x16x32_f16(
                    __builtin_bit_cast(f16x8, bf[nf]), af[mf], acc[mf][nf], 0, 0, 0);
    }

    // Epilogue: D[n][m] layout -> lane holds 4 consecutive n at fixed m.
    const int mrow = mb * 128 + wr * 64;
    const int ncol = nb * 128 + wc * 64;
#pragma unroll
    for (int mf = 0; mf < 4; ++mf) {
        int m_g = mrow + mf * 16 + lr;
        __half* orow = xg + (size_t)m_g * 1280;
#pragma unroll
        for (int nf = 0; nf < 4; ++nf) {
            int n_g = ncol + nf * 16 + kg * 4;
            float4 bv = *(const float4*)(bias_p + n_g);
            f32x4 v = acc[mf][nf];
            union { __half h[4]; uint2 u; } pk;
            pk.h[0] = __float2half(v[0] + bv.x);
            pk.h[1] = __float2half(v[1] + bv.y);
            pk.h[2] = __float2half(v[2] + bv.z);
            pk.h[3] = __float2half(v[3] + bv.w);
            *(uint2*)(orow + n_g) = pk.u;
        }
    }
#undef LOADA
}

// ---------------- Kernel 2: recurrence + pooling ----------------
// One block per chain (dir, sample): 256 blocks x 640 threads.
// xg layout now [b][t][1280]; bwd reads t = 511-step.
__global__ __launch_bounds__(640, 1) void lstm_rec(const uint4* __restrict__ Whh2,
                                                   const __half* __restrict__ xg,
                                                   const int* __restrict__ lens,
                                                   float* __restrict__ out) {
    __shared__ unsigned h2[80];
    __shared__ float gl[GP];
    const int tid = threadIdx.x;
    const int dir = blockIdx.x & 1;
    const int b   = blockIdx.x >> 1;

    uint4 w[20];
    const uint4* wsrc = Whh2 + dir * (20 * 640) + tid;
#pragma unroll
    for (int r = 0; r < 20; ++r) w[r] = wsrc[r * 640];

    if (tid < 80) h2[tid] = 0u;

    float c_s = 0.f, hsum = 0.f, hlast = 0.f;
    int Lv = 1, markLast = -1;
    if (tid < 150) {
        Lv = lens[b];
        markLast = dir ? (Tt - Lv) : (Lv - 1);
    }

    const __half* xbase = xg + (size_t)b * 512 * 1280 + dir * 640 + tid;
    __syncthreads();

    int t0 = dir ? 511 : 0;
    float xv = __half2float(xbase[(size_t)t0 * 1280]);
    const uint4* h4 = (const uint4*)h2;
    for (int step = 0; step < Tt; ++step) {
        int sp = (step + 1 < Tt) ? step + 1 : (Tt - 1);
        int tn = dir ? (511 - sp) : sp;
        __half xn = xbase[(size_t)tn * 1280];   // prefetch next step

        float a0 = xv, a1 = 0.f, a2 = 0.f, a3 = 0.f;
#pragma unroll
        for (int r = 0; r < 20; ++r) {
            uint4 hv = h4[r];
            a0 = fdot2(hv.x, w[r].x, a0);
            a1 = fdot2(hv.y, w[r].y, a1);
            a2 = fdot2(hv.z, w[r].z, a2);
            a3 = fdot2(hv.w, w[r].w, a3);
        }
        gl[tid] = (a0 + a1) + (a2 + a3);
        __syncthreads();

        if (tid < 150) {
            float i_ = sigmoid_fast(gl[tid]);
            float f_ = sigmoid_fast(gl[150 + tid]);
            float g_ = tanh_fast(gl[300 + tid]);
            float o_ = sigmoid_fast(gl[450 + tid]);
            c_s = f_ * c_s + i_ * g_;
            float h = o_ * tanh_fast(c_s);
            bool in = dir ? (step >= markLast) : (step < Lv);
            if (in) hsum += h;
            if (step == markLast) hlast = h;
            ((__half*)h2)[tid] = __float2half(h);
        }
        __syncthreads();
        xv = __half2float(xn);
    }

    if (tid < 150) {
        out[b * 600 + dir * 150 + tid]       = tanh_fast(hsum / (float)Lv);
        out[b * 600 + 300 + dir * 150 + tid] = tanh_fast(hlast);
    }
}

// ---------------- launch ----------------
extern "C" void kernel_launch(void* const* d_in, const int* in_sizes, int n_in,
                              void* d_out, int out_size, void* d_ws, size_t ws_size,
                              hipStream_t stream) {
    const float* x     = (const float*)d_in[0];
    const int*   lens  = (const int*)d_in[1];
    const float* Wih_f = (const float*)d_in[2];
    const float* Whh_f = (const float*)d_in[3];
    const float* b_f   = (const float*)d_in[4];
    const float* Wih_b = (const float*)d_in[5];
    const float* Whh_b = (const float*)d_in[6];
    const float* b_b   = (const float*)d_in[7];
    float* out = (float*)d_out;
    char*  ws  = (char*)d_ws;

    __half*   Bp     = (__half*)(ws + BP16_OFF);
    unsigned* Whh2   = (unsigned*)(ws + WHH2_OFF);
    float*    bias_p = (float*)(ws + BIAS_OFF);
    __half*   xg     = (__half*)(ws + XG_OFF);

    {
        int total = 1280 * 320 + 2 * 20 * 640 * 4 + 1280;
        int blocks = (total + 255) / 256;
        pack_weights<<<blocks, 256, 0, stream>>>(Wih_f, Whh_f, b_f, Wih_b, Whh_b, b_b,
                                                 Bp, Whh2, bias_p);
    }
    {
        gemm_xg<<<5120, 256, 0, stream>>>(x, (const uint4*)Bp, bias_p, xg);
    }
    {
        lstm_rec<<<256, 640, 0, stream>>>((const uint4*)Whh2, xg, lens, out);
    }
}